// Round 7
// baseline (306.264 us; speedup 1.0000x reference)
//
#include <hip/hip_runtime.h>
#include <stdint.h>

#define NF 8192
#define NX 2048
#define MROWS 8192
#define NGROUPS 32
#define NSTEP 64   // NX/32 half-K steps

typedef unsigned short u16;
typedef __bf16 bf16x8 __attribute__((ext_vector_type(8)));
typedef float f32x4 __attribute__((ext_vector_type(4)));

#define AS1 __attribute__((address_space(1)))
#define AS3 __attribute__((address_space(3)))

// async global->LDS, 16B/lane; LDS dest = wave-uniform base + lane*16.
__device__ __forceinline__ void glds16(const void* g, void* l) {
    __builtin_amdgcn_global_load_lds((AS1 void*)(uintptr_t)g,
                                     (AS3 void*)(uintptr_t)l, 16, 0, 0);
}

__device__ __forceinline__ u16 f2bf(float f) {
    unsigned u = __float_as_uint(f);
    return (u16)((u + 0x7FFFu + ((u >> 16) & 1u)) >> 16);  // RNE
}

// packed [NF, NX/2] (one byte per int32, two nibbles) -> W bf16 [NF, NX] row-major.
__global__ void dequant_kernel(const int* __restrict__ packed,
                               const float* __restrict__ scales,
                               const int* __restrict__ zeros,
                               uint32_t* __restrict__ W2) {
    int tid = blockIdx.x * blockDim.x + threadIdx.x;   // [0, NF*NX/2)
    int f = tid >> 10;          // NX/2 = 1024 per row
    int i = tid & 1023;
    int g = f * NGROUPS + (i >> 5);
    int p = packed[tid];
    float s = scales[g];
    float z = (float)zeros[g];
    float w0 = ((float)(p & 15) - z) * s;
    float w1 = ((float)((p >> 4) & 15) - z) * s;
    W2[tid] = (uint32_t)f2bf(w0) | ((uint32_t)f2bf(w1) << 16);
}

// x fp32 -> bf16, 4 elems/thread
__global__ void cvt_kernel(const float4* __restrict__ x, ushort4* __restrict__ y) {
    int i = blockIdx.x * blockDim.x + threadIdx.x;
    float4 v = x[i];
    ushort4 o;
    o.x = f2bf(v.x); o.y = f2bf(v.y); o.z = f2bf(v.z); o.w = f2bf(v.w);
    y[i] = o;
}

// ===========================================================================
// 256x128 tile, 4 waves (2Mx2N), wave tile 128x64, mfma_f32_16x16x32_bf16,
// K processed in 32-wide half-steps (64 steps).  TWO blocks per CU
// (cross-block TLP fills barrier/lgkm stalls -- R6-proven).  LDS ring-3 of
// 24 KiB half-K regions = 72 KiB/block (2 blocks = 144 <= 160).  Per step:
// ONE barrier, 12 ds_reads, 6 glds (stage s+2), lgkm0, 32 MFMA, vmcnt(6).
//
// Wave tile 128x64 halves LDS reads per FLOP vs R6's 64x64 (34.3 vs 45.8
// B/kFLOP) -- R6 measured LDS-traffic-bound, so bytes are the knob.
//
// LDS region (24 KiB): A at +0 (256 rows), B at +16384 (128 rows).
// Row = 64 B (32 k bf16) = 4 x 16B units.  Unit swizzle:
//   content(row, phys u) = k-slot  u ^ ((row>>1)&3).
//   read: lane (l15, quad) of frag: row = base + i*16 + l15,
//         u = ((l15>>1)&3) ^ quad  (base multiples of 16 drop out)
//     -> 16-lane-period form (the empirically zero-conflict family: R1/R6);
//        8-lane groups hit banks {0,4,1,5,2,6,3,7} (hand-verified, all quads).
//   write: glds linear, unit U = t + 256c: row = 64c + (t>>2), phys = t&3,
//          source k-slot = (t&3) ^ ((t>>3)&3)  (c drops out mod 4).
//
// Schedule per step s (regC = s%3 data; regT receives s+2):
//   BAR                       // stage(s) visible: every wave vmcnt-drained
//                             // it at end of step s-1, then barrier
//   12 ds_reads (regC); 6 glds stage(s+2) -> regT
//     WAR-safe: regT was read at s-1; those readers lgkm0-drained before
//     their MFMA(s-1), hence before this BAR, chip-wide.
//   LGKM0 (glds are vmcnt-only); setprio(1); 32 MFMA; setprio(0)
//   vmcnt(6)                  // drains own stage(s+1), leaves stage(s+2)
// Tail: s=62 -> vmcnt(0); s=63 -> none.
// ===========================================================================

#define BAR    __builtin_amdgcn_s_barrier()
#define LGKM0  asm volatile("s_waitcnt lgkmcnt(0)" ::: "memory")
#define VMCNT6 asm volatile("s_waitcnt vmcnt(6)" ::: "memory")
#define VMCNT0 asm volatile("s_waitcnt vmcnt(0)" ::: "memory")
#define FENCE  __builtin_amdgcn_sched_barrier(0)

#define LD8(off) (*(const bf16x8*)(smem + (off)))

#define STAGE6(REG, S) do { \
    const char* _sa = srcA + (size_t)(S) * 64; \
    const char* _sb = srcB + (size_t)(S) * 64; \
    glds16(_sa,          smem + (REG) + t16); \
    glds16(_sa + 262144, smem + (REG) + 4096  + t16); \
    glds16(_sa + 524288, smem + (REG) + 8192  + t16); \
    glds16(_sa + 786432, smem + (REG) + 12288 + t16); \
    glds16(_sb,          smem + (REG) + 16384 + t16); \
    glds16(_sb + 262144, smem + (REG) + 20480 + t16); \
} while (0)

__global__ __launch_bounds__(256, 2)
void gemm_kernel(const u16* __restrict__ A, const u16* __restrict__ B,
                 const float* __restrict__ bias, float* __restrict__ C) {
    __shared__ __align__(16) char smem[73728];   // 3 x 24 KiB ring

    const int t = threadIdx.x;

    // T1: 2-D striped XCD swizzle (R4-proven geometry: FETCH ~295 MB).
    // Grid 2048 = 32 by x 64 bx; each XCD owns 4 by-rows as 2 supers of
    // (2 by x 64 bx), by fastest.
    const int bid = blockIdx.x;
    const int xcd = bid & 7;
    const int local = bid >> 3;          // 0..255
    const int super = local >> 7;        // 0..1
    const int r = local & 127;
    const int by = xcd * 4 + super * 2 + (r & 1);   // 0..31
    const int bx = r >> 1;                          // 0..63
    const int rowA0 = by * 256;
    const int rowB0 = bx * 128;

    // ---- staging addressing (inverse-swizzled global source, linear LDS) ----
    const int t16 = t * 16;
    const int kslot = (t & 3) ^ ((t >> 3) & 3);
    const char* srcA = (const char*)A + (size_t)(rowA0 + (t >> 2)) * 4096 + kslot * 16;
    const char* srcB = (const char*)B + (size_t)(rowB0 + (t >> 2)) * 4096 + kslot * 16;

    // ---- fragment read addressing (16-lane-period, zero-conflict family) ----
    const int lane = t & 63;
    const int wv = t >> 6;
    const int wm = wv >> 1;            // 0..1 (M half, 128 rows)
    const int wn = wv & 1;             // 0..1 (N half, 64 cols)
    const int l15 = lane & 15;
    const int quad = lane >> 4;        // 0..3 = k-slot this lane consumes
    const int uX = ((((l15 >> 1) & 3) ^ quad)) << 4;
    const int aOff = (wm * 128 + l15) * 64 + uX;           // + i*1024
    const int bOff = 16384 + (wn * 64 + l15) * 64 + uX;    // + j*1024

    f32x4 acc[8][4];
#pragma unroll
    for (int i = 0; i < 8; ++i)
#pragma unroll
        for (int j = 0; j < 4; ++j) acc[i][j] = {0.f, 0.f, 0.f, 0.f};

    bf16x8 a[8], b[4];

    // ---- prologue: stage steps 0,1 into regions 0,1; drain step0 ----
    STAGE6(0,     0);
    STAGE6(24576, 1);
    VMCNT6;            // stage(0) done (own); BAR at loop top syncs waves

    int regC = 0, regN = 24576, regT = 49152;

#pragma unroll 1
    for (int s = 0; s < NSTEP; ++s) {
        FENCE; BAR; FENCE;
#pragma unroll
        for (int i = 0; i < 8; ++i) a[i] = LD8(regC + aOff + i * 1024);
#pragma unroll
        for (int j = 0; j < 4; ++j) b[j] = LD8(regC + bOff + j * 1024);
        if (s + 2 < NSTEP) STAGE6(regT, s + 2);   // WAR-safe post-BAR
        FENCE; LGKM0; FENCE;
        __builtin_amdgcn_s_setprio(1);
#pragma unroll
        for (int i = 0; i < 8; ++i)
#pragma unroll
            for (int j = 0; j < 4; ++j)
                acc[i][j] = __builtin_amdgcn_mfma_f32_16x16x32_bf16(a[i], b[j], acc[i][j], 0, 0, 0);
        __builtin_amdgcn_s_setprio(0);
        FENCE;
        if (s + 2 < NSTEP) VMCNT6;                // stage(s+1) landed
        else if (s + 1 < NSTEP) VMCNT0;           // last stage draining

        const int tmp = regC; regC = regN; regN = regT; regT = tmp;
    }

    // ---- epilogue: C/D col = l15, row = quad*4 + e (m89/m91) ----
    const int col0 = rowB0 + wn * 64 + l15;
    const int row0 = rowA0 + wm * 128 + quad * 4;
    float bj[4];
#pragma unroll
    for (int j = 0; j < 4; ++j) bj[j] = bias[col0 + j * 16];
#pragma unroll
    for (int i = 0; i < 8; ++i) {
#pragma unroll
        for (int e = 0; e < 4; ++e) {
            float* crow = C + (size_t)(row0 + i * 16 + e) * NF;
#pragma unroll
            for (int j = 0; j < 4; ++j)
                __builtin_nontemporal_store(acc[i][j][e] + bj[j], crow + col0 + j * 16);
        }
    }
}

extern "C" void kernel_launch(void* const* d_in, const int* in_sizes, int n_in,
                              void* d_out, int out_size, void* d_ws, size_t ws_size,
                              hipStream_t stream) {
    const float* x      = (const float*)d_in[0];   // [4,2048,2048] fp32
    const int* packed   = (const int*)d_in[1];     // [8192,1024]
    const float* scales = (const float*)d_in[2];   // [8192,32]
    const int* zeros    = (const int*)d_in[3];     // [8192,32]
    const float* bias   = (const float*)d_in[4];   // [8192]
    float* out = (float*)d_out;                    // [8192, 8192] fp32

    // workspace: W bf16 (32 MiB) + x bf16 (32 MiB); fully rewritten every call
    u16* Wq = (u16*)d_ws;
    u16* Xb = Wq + (size_t)NF * NX;

    dequant_kernel<<<(NF * (NX / 2)) / 256, 256, 0, stream>>>(packed, scales, zeros, (uint32_t*)Wq);
    cvt_kernel<<<(MROWS * NX / 4) / 256, 256, 0, stream>>>((const float4*)x, (ushort4*)Xb);

    gemm_kernel<<<dim3((MROWS / 256) * (NF / 128)), 256, 0, stream>>>(Xb, Wq, bias, out);
}

// Round 8
// 305.684 us; speedup vs baseline: 1.0019x; 1.0019x over previous
//
#include <hip/hip_runtime.h>
#include <stdint.h>

#define NF 8192
#define NX 2048
#define MROWS 8192
#define NGROUPS 32
#define NSTEP 64   // NX/32 half-K steps

typedef unsigned short u16;
typedef __bf16 bf16x8 __attribute__((ext_vector_type(8)));
typedef float f32x4 __attribute__((ext_vector_type(4)));

#define AS1 __attribute__((address_space(1)))
#define AS3 __attribute__((address_space(3)))

// async global->LDS, 16B/lane; LDS dest = wave-uniform base + lane*16.
__device__ __forceinline__ void glds16(const void* g, void* l) {
    __builtin_amdgcn_global_load_lds((AS1 void*)(uintptr_t)g,
                                     (AS3 void*)(uintptr_t)l, 16, 0, 0);
}

__device__ __forceinline__ u16 f2bf(float f) {
    unsigned u = __float_as_uint(f);
    return (u16)((u + 0x7FFFu + ((u >> 16) & 1u)) >> 16);  // RNE
}

// packed [NF, NX/2] (one byte per int32, two nibbles) -> W bf16 [NF, NX] row-major.
__global__ void dequant_kernel(const int* __restrict__ packed,
                               const float* __restrict__ scales,
                               const int* __restrict__ zeros,
                               uint32_t* __restrict__ W2) {
    int tid = blockIdx.x * blockDim.x + threadIdx.x;   // [0, NF*NX/2)
    int f = tid >> 10;          // NX/2 = 1024 per row
    int i = tid & 1023;
    int g = f * NGROUPS + (i >> 5);
    int p = packed[tid];
    float s = scales[g];
    float z = (float)zeros[g];
    float w0 = ((float)(p & 15) - z) * s;
    float w1 = ((float)((p >> 4) & 15) - z) * s;
    W2[tid] = (uint32_t)f2bf(w0) | ((uint32_t)f2bf(w1) << 16);
}

// x fp32 -> bf16, 4 elems/thread
__global__ void cvt_kernel(const float4* __restrict__ x, ushort4* __restrict__ y) {
    int i = blockIdx.x * blockDim.x + threadIdx.x;
    float4 v = x[i];
    ushort4 o;
    o.x = f2bf(v.x); o.y = f2bf(v.y); o.z = f2bf(v.z); o.w = f2bf(v.w);
    y[i] = o;
}

// ===========================================================================
// 256x128 tile, 4 waves (2Mx2N), wave tile 128x64, mfma_f32_16x16x32_bf16,
// K in 32-wide steps (64 steps).  TWO blocks per CU; LDS ring-3 of 24 KiB
// regions = 72 KiB/block.  R7 geometry (zero-conflict swizzle, FETCH ~310MB)
// + R6's SPLIT LGKM WAIT restored: reads issue {a0-3,b0-3} then {a4-7};
// lgkmcnt(4) gates MFMA half i=0-3 (a4-7 still in flight under the MFMAs),
// lgkmcnt(0) gates half i=4-7.  R7's read-all->drain->MFMA-all serialized
// the LDS and matrix pipes (wall 2681 cyc/step vs work 1694); this split
// restores intra-wave overlap (R6 measured ~180 cyc overhead with it).
//
// LDS region (24 KiB): A at +0 (256 rows), B at +16384 (128 rows).
// Row = 64 B (32 k bf16) = 4 x 16B units; content(row, phys u) = k-slot
// u ^ ((row>>1)&3).
//   read: row = base + i*16 + l15, u = ((l15>>1)&3) ^ quad  -> 16-lane-period
//         form, 8-lane groups hit banks {0,4,1,5,2,6,3,7} (R6/R7 measured 0).
//   write: glds linear, unit U = t + 256c: row = 64c + (t>>2), phys = t&3,
//          source k-slot = (t&3) ^ ((t>>3)&3).
//
// Schedule per step s (regC = data(s); regT receives s+2):
//   BAR; reads a0-3,b0-3; [FENCE] reads a4-7; 6 glds stage(s+2)->regT
//   lgkmcnt(4): MFMA i=0-3 (16)   [first 8 reads done; DS completes in order]
//   lgkmcnt(0): MFMA i=4-7 (16)   [disjoint acc -> halves independent]
//   vmcnt(6): stage(s+1) landed (own); BAR@s+1 publishes cross-wave.
// WAR on regT: its readers (step s-1) lgkm-drained before their MFMA(s-1),
// hence before this BAR.  Tail: s=62 -> vmcnt(0); s=63 -> none.
// ===========================================================================

#define BAR    __builtin_amdgcn_s_barrier()
#define LGKM4  asm volatile("s_waitcnt lgkmcnt(4)" ::: "memory")
#define LGKM0  asm volatile("s_waitcnt lgkmcnt(0)" ::: "memory")
#define VMCNT6 asm volatile("s_waitcnt vmcnt(6)" ::: "memory")
#define VMCNT0 asm volatile("s_waitcnt vmcnt(0)" ::: "memory")
#define FENCE  __builtin_amdgcn_sched_barrier(0)

#define LD8(off) (*(const bf16x8*)(smem + (off)))

#define STAGE6(REG, S) do { \
    const char* _sa = srcA + (size_t)(S) * 64; \
    const char* _sb = srcB + (size_t)(S) * 64; \
    glds16(_sa,          smem + (REG) + t16); \
    glds16(_sa + 262144, smem + (REG) + 4096  + t16); \
    glds16(_sa + 524288, smem + (REG) + 8192  + t16); \
    glds16(_sa + 786432, smem + (REG) + 12288 + t16); \
    glds16(_sb,          smem + (REG) + 16384 + t16); \
    glds16(_sb + 262144, smem + (REG) + 20480 + t16); \
} while (0)

__global__ __launch_bounds__(256, 2)
void gemm_kernel(const u16* __restrict__ A, const u16* __restrict__ B,
                 const float* __restrict__ bias, float* __restrict__ C) {
    __shared__ __align__(16) char smem[73728];   // 3 x 24 KiB ring

    const int t = threadIdx.x;

    // T1: 2-D striped XCD swizzle (R4-proven geometry: FETCH ~300 MB).
    // Grid 2048 = 32 by x 64 bx; each XCD owns 4 by-rows as 2 supers of
    // (2 by x 64 bx), by fastest.
    const int bid = blockIdx.x;
    const int xcd = bid & 7;
    const int local = bid >> 3;          // 0..255
    const int super = local >> 7;        // 0..1
    const int r = local & 127;
    const int by = xcd * 4 + super * 2 + (r & 1);   // 0..31
    const int bx = r >> 1;                          // 0..63
    const int rowA0 = by * 256;
    const int rowB0 = bx * 128;

    // ---- staging addressing (inverse-swizzled global source, linear LDS) ----
    const int t16 = t * 16;
    const int kslot = (t & 3) ^ ((t >> 3) & 3);
    const char* srcA = (const char*)A + (size_t)(rowA0 + (t >> 2)) * 4096 + kslot * 16;
    const char* srcB = (const char*)B + (size_t)(rowB0 + (t >> 2)) * 4096 + kslot * 16;

    // ---- fragment read addressing (16-lane-period, zero-conflict family) ----
    const int lane = t & 63;
    const int wv = t >> 6;
    const int wm = wv >> 1;            // 0..1 (M half, 128 rows)
    const int wn = wv & 1;             // 0..1 (N half, 64 cols)
    const int l15 = lane & 15;
    const int quad = lane >> 4;        // 0..3 = k-slot this lane consumes
    const int uX = ((((l15 >> 1) & 3) ^ quad)) << 4;
    const int aOff = (wm * 128 + l15) * 64 + uX;           // + i*1024
    const int bOff = 16384 + (wn * 64 + l15) * 64 + uX;    // + j*1024

    f32x4 acc[8][4];
#pragma unroll
    for (int i = 0; i < 8; ++i)
#pragma unroll
        for (int j = 0; j < 4; ++j) acc[i][j] = {0.f, 0.f, 0.f, 0.f};

    bf16x8 a[8], b[4];

    // ---- prologue: stage steps 0,1 into regions 0,1; drain step0 ----
    STAGE6(0,     0);
    STAGE6(24576, 1);
    VMCNT6;            // stage(0) done (own); BAR at loop top syncs waves

    int regC = 0, regN = 24576, regT = 49152;

#pragma unroll 1
    for (int s = 0; s < NSTEP; ++s) {
        FENCE; BAR; FENCE;
        // first read group: a0-3 + b0-3 (gates MFMA half 1)
#pragma unroll
        for (int i = 0; i < 4; ++i) a[i] = LD8(regC + aOff + i * 1024);
#pragma unroll
        for (int j = 0; j < 4; ++j) b[j] = LD8(regC + bOff + j * 1024);
        FENCE;   // pin group order (DS completes in order; lgkmcnt(4) => first 8 done)
        // second read group: a4-7
#pragma unroll
        for (int i = 4; i < 8; ++i) a[i] = LD8(regC + aOff + i * 1024);
        if (s + 2 < NSTEP) STAGE6(regT, s + 2);   // vmcnt-counted; WAR-safe post-BAR
        FENCE; LGKM4; FENCE;                      // a0-3,b0-3 ready
        __builtin_amdgcn_s_setprio(1);
#pragma unroll
        for (int i = 0; i < 4; ++i)
#pragma unroll
            for (int j = 0; j < 4; ++j)
                acc[i][j] = __builtin_amdgcn_mfma_f32_16x16x32_bf16(a[i], b[j], acc[i][j], 0, 0, 0);
        __builtin_amdgcn_s_setprio(0);
        FENCE; LGKM0; FENCE;                      // a4-7 ready (hid under MFMAs)
        __builtin_amdgcn_s_setprio(1);
#pragma unroll
        for (int i = 4; i < 8; ++i)
#pragma unroll
            for (int j = 0; j < 4; ++j)
                acc[i][j] = __builtin_amdgcn_mfma_f32_16x16x32_bf16(a[i], b[j], acc[i][j], 0, 0, 0);
        __builtin_amdgcn_s_setprio(0);
        FENCE;
        if (s + 2 < NSTEP) VMCNT6;                // stage(s+1) landed
        else if (s + 1 < NSTEP) VMCNT0;           // last stage draining

        const int tmp = regC; regC = regN; regN = regT; regT = tmp;
    }

    // ---- epilogue: C/D col = l15, row = quad*4 + e (m89/m91) ----
    const int col0 = rowB0 + wn * 64 + l15;
    const int row0 = rowA0 + wm * 128 + quad * 4;
    float bj[4];
#pragma unroll
    for (int j = 0; j < 4; ++j) bj[j] = bias[col0 + j * 16];
#pragma unroll
    for (int i = 0; i < 8; ++i) {
#pragma unroll
        for (int e = 0; e < 4; ++e) {
            float* crow = C + (size_t)(row0 + i * 16 + e) * NF;
#pragma unroll
            for (int j = 0; j < 4; ++j)
                __builtin_nontemporal_store(acc[i][j][e] + bj[j], crow + col0 + j * 16);
        }
    }
}

extern "C" void kernel_launch(void* const* d_in, const int* in_sizes, int n_in,
                              void* d_out, int out_size, void* d_ws, size_t ws_size,
                              hipStream_t stream) {
    const float* x      = (const float*)d_in[0];   // [4,2048,2048] fp32
    const int* packed   = (const int*)d_in[1];     // [8192,1024]
    const float* scales = (const float*)d_in[2];   // [8192,32]
    const int* zeros    = (const int*)d_in[3];     // [8192,32]
    const float* bias   = (const float*)d_in[4];   // [8192]
    float* out = (float*)d_out;                    // [8192, 8192] fp32

    // workspace: W bf16 (32 MiB) + x bf16 (32 MiB); fully rewritten every call
    u16* Wq = (u16*)d_ws;
    u16* Xb = Wq + (size_t)NF * NX;

    dequant_kernel<<<(NF * (NX / 2)) / 256, 256, 0, stream>>>(packed, scales, zeros, (uint32_t*)Wq);
    cvt_kernel<<<(MROWS * NX / 4) / 256, 256, 0, stream>>>((const float4*)x, (ushort4*)Xb);

    gemm_kernel<<<dim3((MROWS / 256) * (NF / 128)), 256, 0, stream>>>(Xb, Wq, bias, out);
}